// Round 2
// baseline (404.200 us; speedup 1.0000x reference)
//
#include <hip/hip_runtime.h>
#include <hip/hip_bf16.h>

using u16 = unsigned short;
typedef __attribute__((ext_vector_type(4))) float f32x4;
typedef __attribute__((ext_vector_type(8))) short s16x8;
typedef __attribute__((ext_vector_type(4))) unsigned short u16x4;

#define MFMA(a,b,c) __builtin_amdgcn_mfma_f32_16x16x32_bf16((a),(b),(c),0,0,0)

__device__ __forceinline__ u16 f2bf(float f){
  unsigned u = __builtin_bit_cast(unsigned, f);
  u += 0x7fff + ((u >> 16) & 1);          // RNE
  return (u16)(u >> 16);
}
__device__ __forceinline__ float bf2f(u16 h){
  unsigned u = ((unsigned)h) << 16;
  return __builtin_bit_cast(float, u);
}
__device__ __forceinline__ float sigm(float x){
  return 1.f / (1.f + __expf(-x));
}

// ---------------- K0: weights fp32 -> bf16, concatenated [Wproj;Wgate;Wglin] ----------------
__global__ void k0_prep(const float* __restrict__ Wp, const float* __restrict__ Wg,
                        const float* __restrict__ Wgl, const float* __restrict__ Wo,
                        u16* __restrict__ Wc, u16* __restrict__ WoB){
  int idx = blockIdx.x * 256 + threadIdx.x;   // grid covers 640*128 exactly
  if (idx < 640 * 128){
    int n = idx >> 7, k = idx & 127;
    float v;
    if (n < 256)      v = Wp[n * 128 + k];
    else if (n < 512) v = Wg[(n - 256) * 128 + k];
    else              v = Wgl[(n - 512) * 128 + k];
    Wc[idx] = f2bf(v);
  }
  if (idx < 128 * 128) WoB[idx] = f2bf(Wo[idx]);
}

// ---------------- K1: LN1 + x@[Wproj|Wgate|Wglin]^T + mask*sigmoid pairing ----------------
// Tile = 128 tokens in a COLUMN of the token matrix: t1 in [k0,k0+128), t2 = j fixed.
// Writes a_r[c][t2][t1], b_r[c][t2][t1] (K-contiguous for K2) and g[t1][t2][c] = sigmoid(glin).
__launch_bounds__(256, 2)
__global__ void k1_ln_proj(const float* __restrict__ pair, const float* __restrict__ mask,
                           const float* __restrict__ ln1w, const float* __restrict__ ln1b,
                           const u16* __restrict__ Wc,
                           u16* __restrict__ a_r, u16* __restrict__ b_r, u16* __restrict__ g){
  __shared__ float red_s[128], red_q[128], msk[128];
  __shared__ u16 xs[128 * 136];              // LN1 output, bf16, padded stride 136
  int tid = threadIdx.x;
  int bid = blockIdx.x;
  int j   = bid >> 2;
  int k0  = (bid & 3) << 7;

  // Phase A: load 128x128 fp32 tile (coalesced), per-token LN stats via 32-lane shuffles
  int cpos = tid & 31;                       // float4 slot within a token row
  int rsub = tid >> 5;                       // 0..7
  float4 v[16];
  #pragma unroll
  for (int it = 0; it < 16; ++it){
    int kk = it * 8 + rsub;
    const float4* p = (const float4*)(pair + (((size_t)(k0 + kk) * 512 + j) << 7));
    v[it] = p[cpos];
    float s = v[it].x + v[it].y + v[it].z + v[it].w;
    float q = v[it].x*v[it].x + v[it].y*v[it].y + v[it].z*v[it].z + v[it].w*v[it].w;
    #pragma unroll
    for (int m = 16; m >= 1; m >>= 1){
      s += __shfl_xor(s, m);
      q += __shfl_xor(q, m);
    }
    if (cpos == 0){ red_s[kk] = s; red_q[kk] = q; }
  }
  if (tid < 128) msk[tid] = mask[(size_t)(k0 + tid) * 512 + j];
  __syncthreads();

  float4 w4 = ((const float4*)ln1w)[cpos];
  float4 b4 = ((const float4*)ln1b)[cpos];
  #pragma unroll
  for (int it = 0; it < 16; ++it){
    int kk = it * 8 + rsub;
    float mu = red_s[kk] * (1.f / 128.f);
    float var = red_q[kk] * (1.f / 128.f) - mu * mu;
    float rs = rsqrtf(var + 1e-5f);
    u16x4 o;
    o[0] = f2bf((v[it].x - mu) * rs * w4.x + b4.x);
    o[1] = f2bf((v[it].y - mu) * rs * w4.y + b4.y);
    o[2] = f2bf((v[it].z - mu) * rs * w4.z + b4.z);
    o[3] = f2bf((v[it].w - mu) * rs * w4.w + b4.w);
    *(u16x4*)&xs[kk * 136 + cpos * 4] = o;
  }
  __syncthreads();

  // Phase B: MFMA. M=128 (tokens), K=128, N=640 (proj 0..255 | gate 256..511 | glin 512..639)
  int lane = tid & 63;
  int wv   = tid >> 6;
  int l15  = lane & 15;
  int l4   = lane >> 4;

  // paired proj/gate n-tiles: wave handles tp = pi*4+wv
  for (int pi = 0; pi < 4; ++pi){
    int tp = pi * 4 + wv;                    // 0..15
    int nP = tp * 16 + l15;                  // proj column 0..255
    f32x4 accP[8] = {}; f32x4 accG[8] = {};
    #pragma unroll
    for (int ks = 0; ks < 4; ++ks){
      s16x8 bP = *(const s16x8*)&Wc[nP * 128 + ks * 32 + l4 * 8];
      s16x8 bG = *(const s16x8*)&Wc[(256 + nP) * 128 + ks * 32 + l4 * 8];
      #pragma unroll
      for (int mi = 0; mi < 8; ++mi){
        s16x8 af = *(const s16x8*)&xs[(mi * 16 + l15) * 136 + ks * 32 + l4 * 8];
        accP[mi] = MFMA(af, bP, accP[mi]);
        accG[mi] = MFMA(af, bG, accG[mi]);
      }
    }
    int c = nP >> 1;
    u16* dst = (nP & 1) ? b_r : a_r;
    #pragma unroll
    for (int mi = 0; mi < 8; ++mi){
      int m0 = mi * 16 + l4 * 4;
      u16x4 o;
      #pragma unroll
      for (int r = 0; r < 4; ++r){
        float p = accP[mi][r] * msk[m0 + r] * sigm(accG[mi][r]);
        o[r] = f2bf(p);
      }
      *(u16x4*)&dst[((size_t)c * 512 + j) * 512 + k0 + m0] = o;
    }
  }

  // glin n-tiles -> g (token-major, sigmoid applied)
  for (int gi = 0; gi < 2; ++gi){
    int tg = gi * 4 + wv;                    // 0..7
    int cg = tg * 16 + l15;                  // 0..127
    f32x4 acc[8] = {};
    #pragma unroll
    for (int ks = 0; ks < 4; ++ks){
      s16x8 bW = *(const s16x8*)&Wc[(512 + cg) * 128 + ks * 32 + l4 * 8];
      #pragma unroll
      for (int mi = 0; mi < 8; ++mi){
        s16x8 af = *(const s16x8*)&xs[(mi * 16 + l15) * 136 + ks * 32 + l4 * 8];
        acc[mi] = MFMA(af, bW, acc[mi]);
      }
    }
    #pragma unroll
    for (int mi = 0; mi < 8; ++mi){
      int m0 = mi * 16 + l4 * 4;
      #pragma unroll
      for (int r = 0; r < 4; ++r){
        g[(((size_t)(k0 + m0 + r) * 512 + j) << 7) + cg] = f2bf(sigm(acc[mi][r]));
      }
    }
  }
}

// ---------------- K2: triangle einsum, 128 per-channel 512x512x512 bf16 GEMMs ----------------
// out_r[c][i][j] = sum_k b_r[c][i][k] * a_r[c][j][k]  (NT GEMM, direct global frag loads)
__launch_bounds__(256, 2)
__global__ void k2_tri(const u16* __restrict__ a_r, const u16* __restrict__ b_r,
                       u16* __restrict__ out_r){
  int tid = threadIdx.x, bid = blockIdx.x;
  int c  = bid >> 4;
  int t  = bid & 15;
  int lane = tid & 63, wv = tid >> 6;
  int i0 = (t >> 2) * 128 + (wv >> 1) * 64;
  int j0 = (t & 3) * 128 + (wv & 1) * 64;
  int l15 = lane & 15, l4 = lane >> 4;
  const u16* pa = a_r + (size_t)c * 262144;
  const u16* pb = b_r + (size_t)c * 262144;

  f32x4 acc[4][4] = {};
  for (int ks = 0; ks < 16; ++ks){
    s16x8 A[4], B[4];
    #pragma unroll
    for (int ai = 0; ai < 4; ++ai)
      A[ai] = *(const s16x8*)&pb[(i0 + ai * 16 + l15) * 512 + ks * 32 + l4 * 8];
    #pragma unroll
    for (int bj = 0; bj < 4; ++bj)
      B[bj] = *(const s16x8*)&pa[(j0 + bj * 16 + l15) * 512 + ks * 32 + l4 * 8];
    #pragma unroll
    for (int ai = 0; ai < 4; ++ai)
      #pragma unroll
      for (int bj = 0; bj < 4; ++bj)
        acc[ai][bj] = MFMA(A[ai], B[bj], acc[ai][bj]);
  }
  u16* po = out_r + (size_t)c * 262144;
  #pragma unroll
  for (int ai = 0; ai < 4; ++ai){
    #pragma unroll
    for (int r = 0; r < 4; ++r){
      int i = i0 + ai * 16 + l4 * 4 + r;
      #pragma unroll
      for (int bj = 0; bj < 4; ++bj)
        po[i * 512 + j0 + bj * 16 + l15] = f2bf(acc[ai][bj][r]);
    }
  }
}

// ---------------- K3: LN2 + @W_out^T + sigmoid(glin) gating -> fp32 out ----------------
__launch_bounds__(256, 2)
__global__ void k3_out(const u16* __restrict__ out_r, const u16* __restrict__ g,
                       const float* __restrict__ ln2w, const float* __restrict__ ln2b,
                       const u16* __restrict__ WoB, float* __restrict__ out){
  __shared__ u16 ot[128 * 72];               // out_r gather tile [cin][jj], padded
  __shared__ u16 x2[64 * 136];               // LN2 output [jj][cin], padded
  int tid = threadIdx.x, bid = blockIdx.x;
  int i  = bid >> 3;                         // first token index
  int j0 = (bid & 7) << 6;                   // 64-token j block

  // gather: 128 channels x 16 parts (u16x4 each) = 2048 loads -> 8 iters of 256 threads
  #pragma unroll
  for (int it = 0; it < 8; ++it){
    int f = it * 256 + tid;
    int cin = f >> 4, part = f & 15;
    u16x4 vld = *(const u16x4*)&out_r[(size_t)cin * 262144 + i * 512 + j0 + part * 4];
    *(u16x4*)&ot[cin * 72 + part * 4] = vld;
  }
  __syncthreads();

  // LN2: 4 threads per token (32 channels each), shuffle-combine
  int jj = tid >> 2, qr = tid & 3;
  float s = 0.f, q = 0.f;
  #pragma unroll
  for (int u = 0; u < 32; ++u){
    float x = bf2f(ot[(qr * 32 + u) * 72 + jj]);
    s += x; q += x * x;
  }
  s += __shfl_xor(s, 1); q += __shfl_xor(q, 1);
  s += __shfl_xor(s, 2); q += __shfl_xor(q, 2);
  float mu = s * (1.f / 128.f);
  float rs = rsqrtf(q * (1.f / 128.f) - mu * mu + 1e-5f);
  #pragma unroll
  for (int u = 0; u < 32; ++u){
    int cin = qr * 32 + u;
    float x = bf2f(ot[cin * 72 + jj]);
    x2[jj * 136 + cin] = f2bf((x - mu) * rs * ln2w[cin] + ln2b[cin]);
  }
  __syncthreads();

  // GEMM: 64 tokens x 128 cout x 128 cin; wave handles 32 cout
  int lane = tid & 63, wv = tid >> 6;
  int l15 = lane & 15, l4 = lane >> 4;
  int n0 = wv * 32;
  f32x4 acc[4][2] = {};
  #pragma unroll
  for (int ks = 0; ks < 4; ++ks){
    s16x8 B0 = *(const s16x8*)&WoB[(n0 + l15) * 128 + ks * 32 + l4 * 8];
    s16x8 B1 = *(const s16x8*)&WoB[(n0 + 16 + l15) * 128 + ks * 32 + l4 * 8];
    #pragma unroll
    for (int mi = 0; mi < 4; ++mi){
      s16x8 A = *(const s16x8*)&x2[(mi * 16 + l15) * 136 + ks * 32 + l4 * 8];
      acc[mi][0] = MFMA(A, B0, acc[mi][0]);
      acc[mi][1] = MFMA(A, B1, acc[mi][1]);
    }
  }
  #pragma unroll
  for (int mi = 0; mi < 4; ++mi){
    #pragma unroll
    for (int r = 0; r < 4; ++r){
      int m = mi * 16 + l4 * 4 + r;
      size_t tok = (size_t)i * 512 + j0 + m;
      #pragma unroll
      for (int nj = 0; nj < 2; ++nj){
        int cout = n0 + nj * 16 + l15;
        float gv = bf2f(g[tok * 128 + cout]);
        out[tok * 128 + cout] = acc[mi][nj][r] * gv;
      }
    }
  }
}

extern "C" void kernel_launch(void* const* d_in, const int* in_sizes, int n_in,
                              void* d_out, int out_size, void* d_ws, size_t ws_size,
                              hipStream_t stream){
  (void)in_sizes; (void)n_in; (void)out_size; (void)ws_size;
  const float* pair = (const float*)d_in[0];
  const float* mask = (const float*)d_in[1];
  const float* ln1w = (const float*)d_in[2];
  const float* ln1b = (const float*)d_in[3];
  const float* ln2w = (const float*)d_in[4];
  const float* ln2b = (const float*)d_in[5];
  const float* Wp   = (const float*)d_in[6];
  const float* Wg   = (const float*)d_in[7];
  const float* Wo   = (const float*)d_in[8];   // W_out comes BEFORE W_glin in dict order
  const float* Wgl  = (const float*)d_in[9];
  float* out = (float*)d_out;

  char* ws = (char*)d_ws;
  u16* a_r = (u16*)(ws);                         // 67108864 B  a_r[c][j][k]
  u16* b_r = (u16*)(ws + 67108864);              // 67108864 B  b_r[c][i][k]
  u16* g   = (u16*)(ws + 134217728);             // 67108864 B  sigmoid(glin), token-major
  u16* o_r = (u16*)(ws + 201326592);             // 67108864 B  out_r[c][i][j]
  u16* Wc  = (u16*)(ws + 268435456);             // 163840 B
  u16* WoB = (u16*)(ws + 268435456 + 163840);    // 32768 B

  hipLaunchKernelGGL(k0_prep,   dim3(320),  dim3(256), 0, stream, Wp, Wg, Wgl, Wo, Wc, WoB);
  hipLaunchKernelGGL(k1_ln_proj,dim3(2048), dim3(256), 0, stream, pair, mask, ln1w, ln1b, Wc, a_r, b_r, g);
  hipLaunchKernelGGL(k2_tri,    dim3(2048), dim3(256), 0, stream, a_r, b_r, o_r);
  hipLaunchKernelGGL(k3_out,    dim3(4096), dim3(256), 0, stream, o_r, g, ln2w, ln2b, WoB, out);
}